// Round 3
// baseline (951.471 us; speedup 1.0000x reference)
//
#include <hip/hip_runtime.h>
#include <hip/hip_bf16.h>
#include <math.h>

// ---------------------------------------------------------------------------
// GATv2 backbone: 3 layers, fixed graph. Phases per call:
//   1. CSR build by destination (self-loops inserted first per node)
//   2. per layer: two fp32 GEMMs (xl = H@Wl+bl, xr = H@Wr+br)
//   3. per layer: wave-per-node online-softmax aggregation (no atomics in fp)
// ---------------------------------------------------------------------------

#define DIN   256
#define HDMID 256   // H*Dh for layers 0/1 (8*32)
#define HDOUT 512   // H*Dh for layer 2 (8*64)
#define DOUT  64

// ---------------- CSR build ----------------

__global__ void k_init_cnt(int* cnt, int n) {
    int i = blockIdx.x * blockDim.x + threadIdx.x;
    if (i < n) cnt[i] = 1;   // self-loop pre-counted
}

__global__ void k_count(const int* __restrict__ ei, int* cnt, int E) {
    int e = blockIdx.x * blockDim.x + threadIdx.x;
    if (e < E) atomicAdd(&cnt[ei[E + e]], 1);   // dst row
}

__global__ void k_scan(const int* __restrict__ cnt, int* __restrict__ row_ptr, int n) {
    __shared__ int sm[256];
    int tid = threadIdx.x;
    int carry = 0;
    if (tid == 0) row_ptr[0] = 0;
    for (int base = 0; base < n; base += 256) {
        int i = base + tid;
        int v = (i < n) ? cnt[i] : 0;
        sm[tid] = v;
        __syncthreads();
        for (int off = 1; off < 256; off <<= 1) {
            int t = (tid >= off) ? sm[tid - off] : 0;
            __syncthreads();
            sm[tid] += t;
            __syncthreads();
        }
        if (i < n) row_ptr[i + 1] = carry + sm[tid];
        carry += sm[255];
        __syncthreads();
    }
}

__global__ void k_selfloop(const int* __restrict__ row_ptr, int* __restrict__ csr_src,
                           int* __restrict__ cnt, int n) {
    int v = blockIdx.x * blockDim.x + threadIdx.x;
    if (v < n) {
        csr_src[row_ptr[v]] = v;   // self-loop at slot 0
        cnt[v] = 1;                // fill counter restarts after the self-loop
    }
}

__global__ void k_scatter(const int* __restrict__ ei, const int* __restrict__ row_ptr,
                          int* __restrict__ cnt, int* __restrict__ csr_src, int E) {
    int e = blockIdx.x * blockDim.x + threadIdx.x;
    if (e < E) {
        int d = ei[E + e];
        int pos = row_ptr[d] + atomicAdd(&cnt[d], 1);
        csr_src[pos] = ei[e];
    }
}

// ---------------- fp32 tiled GEMM: C = A[M,K] @ W[K,N] + bias[N] ----------------
// 128x64 tile, BK=16, 256 threads, 8x4 micro-tile. Micro-tile rows are
// ty + 16*i (stride-16) so the per-wave A-column LDS read lands 2 addrs/bank
// (2-way aliasing = free) instead of 4-way at contiguous rows.

#define BM 128
#define BN 64
#define BK 16

__global__ __launch_bounds__(256) void gemm_bias(
    const float* __restrict__ A, const float* __restrict__ W,
    const float* __restrict__ bias, float* __restrict__ C,
    int M, int K, int N) {
    __shared__ float As[BM][BK];   // 8 KB, unpadded so float4 stores stay aligned
    __shared__ float Bs[BK][BN];   // 4 KB
    int tid = threadIdx.x;
    int tx = tid & 15, ty = tid >> 4;   // tx: col group (x4), ty: row base (stride 16)
    int row0 = blockIdx.y * BM, col0 = blockIdx.x * BN;
    float acc[8][4] = {};

    for (int k0 = 0; k0 < K; k0 += BK) {
        // stage A tile 128x16: 512 float4, 2 per thread
        #pragma unroll
        for (int h = 0; h < 2; ++h) {
            int q = tid * 2 + h;
            int r = q >> 2, c = (q & 3) * 4;
            int gr = row0 + r;
            float4 f = make_float4(0.f, 0.f, 0.f, 0.f);
            if (gr < M) f = *reinterpret_cast<const float4*>(&A[(size_t)gr * K + k0 + c]);
            *reinterpret_cast<float4*>(&As[r][c]) = f;
        }
        // stage B tile 16x64: 256 float4, 1 per thread
        {
            int r = tid >> 4, c = (tid & 15) * 4;
            float4 f = *reinterpret_cast<const float4*>(&W[(size_t)(k0 + r) * N + col0 + c]);
            *reinterpret_cast<float4*>(&Bs[r][c]) = f;
        }
        __syncthreads();
        #pragma unroll
        for (int kk = 0; kk < BK; ++kk) {
            float a[8];
            #pragma unroll
            for (int i = 0; i < 8; ++i) a[i] = As[ty + 16 * i][kk];
            float4 bv = *reinterpret_cast<const float4*>(&Bs[kk][tx * 4]);
            float b[4] = {bv.x, bv.y, bv.z, bv.w};
            #pragma unroll
            for (int i = 0; i < 8; ++i)
                #pragma unroll
                for (int j = 0; j < 4; ++j)
                    acc[i][j] += a[i] * b[j];
        }
        __syncthreads();
    }

    float4 bb = *reinterpret_cast<const float4*>(&bias[col0 + tx * 4]);
    #pragma unroll
    for (int i = 0; i < 8; ++i) {
        int r = row0 + ty + 16 * i;
        if (r < M) {
            float4 o;
            o.x = acc[i][0] + bb.x;
            o.y = acc[i][1] + bb.y;
            o.z = acc[i][2] + bb.z;
            o.w = acc[i][3] + bb.w;
            *reinterpret_cast<float4*>(&C[(size_t)r * N + col0 + tx * 4]) = o;
        }
    }
}

// ---------------- wave-per-node aggregation with online softmax ----------------
// HD = H*Dh (flat feature width), DH = per-head dim.
// lane l owns elements idx = l + 64*j; for DH=32 the e-reduction group is a
// 32-lane half-wave, for DH=64 the full wave. MODE: 0 = elu(+bias) store,
// 1 = elu(+bias)+resid store, 2 = head-mean (+bias) store (layer 2).

template<int HD, int DH, int MODE>
__global__ __launch_bounds__(256) void gat_aggregate(
    const float* __restrict__ xl, const float* __restrict__ xr,
    const float* __restrict__ att, const int* __restrict__ row_ptr,
    const int* __restrict__ csr_src, const float* __restrict__ bias,
    const float* __restrict__ resid, float* __restrict__ out, int n) {
    constexpr int J = HD / 64;
    int wid  = threadIdx.x >> 6;
    int lane = threadIdx.x & 63;
    int v = blockIdx.x * 4 + wid;
    if (v >= n) return;

    float xrv[J], attv[J], acc[J], lsum[J], mval[J];
    #pragma unroll
    for (int j = 0; j < J; ++j) {
        int idx = lane + 64 * j;
        xrv[j]  = xr[(size_t)v * HD + idx];
        attv[j] = att[idx];
        acc[j] = 0.f; lsum[j] = 0.f; mval[j] = -INFINITY;
    }

    int e0 = row_ptr[v], e1 = row_ptr[v + 1];
    for (int e = e0; e < e1; ++e) {
        int s = csr_src[e];
        float xlv[J], p[J];
        #pragma unroll
        for (int j = 0; j < J; ++j) {
            xlv[j] = xl[(size_t)s * HD + lane + 64 * j];
            float m  = xlv[j] + xrv[j];
            float lr = m > 0.f ? m : 0.2f * m;
            p[j] = lr * attv[j];
        }
        #pragma unroll
        for (int off = 1; off < ((DH == 64) ? 64 : 32); off <<= 1) {
            #pragma unroll
            for (int j = 0; j < J; ++j) p[j] += __shfl_xor(p[j], off);
        }
        #pragma unroll
        for (int j = 0; j < J; ++j) {
            float ev = p[j];
            if (ev > mval[j]) {
                float sc = __expf(mval[j] - ev);
                acc[j] *= sc; lsum[j] *= sc; mval[j] = ev;
            }
            float pe = __expf(ev - mval[j]);
            lsum[j] += pe;
            acc[j]  += pe * xlv[j];
        }
    }

    if (MODE == 2) {
        float s = 0.f;
        #pragma unroll
        for (int j = 0; j < J; ++j) s += acc[j] / lsum[j];
        out[(size_t)v * DOUT + lane] = s * (1.f / 8.f) + bias[lane];
    } else {
        #pragma unroll
        for (int j = 0; j < J; ++j) {
            int idx = lane + 64 * j;
            float a = acc[j] / lsum[j] + bias[idx];
            float ev = a > 0.f ? a : (__expf(a) - 1.f);
            if (MODE == 1) ev += resid[(size_t)v * HD + idx];
            out[(size_t)v * HD + idx] = ev;
        }
    }
}

// ---------------------------------------------------------------------------

extern "C" void kernel_launch(void* const* d_in, const int* in_sizes, int n_in,
                              void* d_out, int out_size, void* d_ws, size_t ws_size,
                              hipStream_t stream) {
    const float* x     = (const float*)d_in[0];
    const int*   ei    = (const int*)  d_in[1];
    const float* Wl0   = (const float*)d_in[2];
    const float* bl0   = (const float*)d_in[3];
    const float* Wr0   = (const float*)d_in[4];
    const float* br0   = (const float*)d_in[5];
    const float* att0  = (const float*)d_in[6];
    const float* bias0 = (const float*)d_in[7];
    const float* Wl1   = (const float*)d_in[8];
    const float* bl1   = (const float*)d_in[9];
    const float* Wr1   = (const float*)d_in[10];
    const float* br1   = (const float*)d_in[11];
    const float* att1  = (const float*)d_in[12];
    const float* bias1 = (const float*)d_in[13];
    const float* Wl2   = (const float*)d_in[14];
    const float* bl2   = (const float*)d_in[15];
    const float* Wr2   = (const float*)d_in[16];
    const float* br2   = (const float*)d_in[17];
    const float* att2  = (const float*)d_in[18];
    const float* bias2 = (const float*)d_in[19];

    const int N = in_sizes[0] / DIN;       // 20000
    const int E = in_sizes[1] / 2;         // 320000

    char* ws = (char*)d_ws;
    size_t off = 0;
    auto carve = [&](size_t bytes) {
        void* p = ws + off;
        off = (off + bytes + 15) & ~(size_t)15;
        return p;
    };
    int*   row_ptr = (int*)  carve((size_t)(N + 1) * 4);
    int*   cnt     = (int*)  carve((size_t)N * 4);
    int*   csr_src = (int*)  carve((size_t)(E + N) * 4);
    float* xl      = (float*)carve((size_t)N * HDOUT * 4);
    float* xr      = (float*)carve((size_t)N * HDOUT * 4);
    float* h1      = (float*)carve((size_t)N * HDMID * 4);
    float* h2      = (float*)carve((size_t)N * HDMID * 4);

    float* outp = (float*)d_out;

    // ---- CSR build ----
    k_init_cnt<<<(N + 255) / 256, 256, 0, stream>>>(cnt, N);
    k_count   <<<(E + 255) / 256, 256, 0, stream>>>(ei, cnt, E);
    k_scan    <<<1, 256, 0, stream>>>(cnt, row_ptr, N);
    k_selfloop<<<(N + 255) / 256, 256, 0, stream>>>(row_ptr, csr_src, cnt, N);
    k_scatter <<<(E + 255) / 256, 256, 0, stream>>>(ei, row_ptr, cnt, csr_src, E);

    dim3 blk(256);

    // ---- layer 0 ----
    {
        dim3 grid(HDMID / BN, (N + BM - 1) / BM);
        gemm_bias<<<grid, blk, 0, stream>>>(x, Wl0, bl0, xl, N, DIN, HDMID);
        gemm_bias<<<grid, blk, 0, stream>>>(x, Wr0, br0, xr, N, DIN, HDMID);
        gat_aggregate<HDMID, 32, 0><<<(N + 3) / 4, blk, 0, stream>>>(
            xl, xr, att0, row_ptr, csr_src, bias0, nullptr, h1, N);
    }
    // ---- layer 1 ----
    {
        dim3 grid(HDMID / BN, (N + BM - 1) / BM);
        gemm_bias<<<grid, blk, 0, stream>>>(h1, Wl1, bl1, xl, N, HDMID, HDMID);
        gemm_bias<<<grid, blk, 0, stream>>>(h1, Wr1, br1, xr, N, HDMID, HDMID);
        gat_aggregate<HDMID, 32, 1><<<(N + 3) / 4, blk, 0, stream>>>(
            xl, xr, att1, row_ptr, csr_src, bias1, h1, h2, N);
    }
    // ---- layer 2 ----
    {
        dim3 grid(HDOUT / BN, (N + BM - 1) / BM);
        gemm_bias<<<grid, blk, 0, stream>>>(h2, Wl2, bl2, xl, N, HDMID, HDOUT);
        gemm_bias<<<grid, blk, 0, stream>>>(h2, Wr2, br2, xr, N, HDMID, HDOUT);
        gat_aggregate<HDOUT, 64, 2><<<(N + 3) / 4, blk, 0, stream>>>(
            xl, xr, att2, row_ptr, csr_src, bias2, nullptr, outp, N);
    }
}

// Round 7
// 656.919 us; speedup vs baseline: 1.4484x; 1.4484x over previous
//
#include <hip/hip_runtime.h>
#include <math.h>

// ---------------------------------------------------------------------------
// GATv2 backbone, round 7 (= round 4/5 design, resubmitted through GPU
// acquisition timeouts; audited 3x, never yet executed):
//   - GEMMs: 3-term split-bf16 MFMA (Ah*Wh + Al*Wh + Ah*Wl), fp32 accumulate.
//     128x128 tile / BK=64 / 4 waves / 16x16x32 bf16 frags, XOR-swizzled LDS
//     (both-sides swizzle via reg staging).
//   - Aggregates: float4-per-lane ownership, batched-edge gathers (8 mid /
//     4 out rows in flight) for latency hiding, online softmax in registers.
//   - Activation bf16 splits fused into aggregate epilogues; layer-1 residual
//     reconstructed from the hi/lo splits (no fp32 h buffer).
// ---------------------------------------------------------------------------

#define DIN   256
#define NNODE_K 256   // K is 256 for every GEMM in this net

typedef __attribute__((ext_vector_type(8))) short short8v;
typedef __attribute__((ext_vector_type(4))) float floatx4;

static __device__ __forceinline__ unsigned short f2bf(float f) {
    unsigned int u = __float_as_uint(f);
    unsigned int r = (u + 0x7FFFu + ((u >> 16) & 1u)) >> 16;   // RNE
    return (unsigned short)r;
}
static __device__ __forceinline__ float bf2f(unsigned short h) {
    return __uint_as_float(((unsigned int)h) << 16);
}
static __device__ __forceinline__ float lrelu(float m) {
    return m > 0.f ? m : 0.2f * m;
}

// ---------------- CSR build (unchanged from passing round) ----------------

__global__ void k_init_cnt(int* cnt, int n) {
    int i = blockIdx.x * blockDim.x + threadIdx.x;
    if (i < n) cnt[i] = 1;   // self-loop pre-counted
}

__global__ void k_count(const int* __restrict__ ei, int* cnt, int E) {
    int e = blockIdx.x * blockDim.x + threadIdx.x;
    if (e < E) atomicAdd(&cnt[ei[E + e]], 1);   // dst row
}

__global__ void k_scan(const int* __restrict__ cnt, int* __restrict__ row_ptr, int n) {
    __shared__ int sm[256];
    int tid = threadIdx.x;
    int carry = 0;
    if (tid == 0) row_ptr[0] = 0;
    for (int base = 0; base < n; base += 256) {
        int i = base + tid;
        int v = (i < n) ? cnt[i] : 0;
        sm[tid] = v;
        __syncthreads();
        for (int off = 1; off < 256; off <<= 1) {
            int t = (tid >= off) ? sm[tid - off] : 0;
            __syncthreads();
            sm[tid] += t;
            __syncthreads();
        }
        if (i < n) row_ptr[i + 1] = carry + sm[tid];
        carry += sm[255];
        __syncthreads();
    }
}

__global__ void k_selfloop(const int* __restrict__ row_ptr, int* __restrict__ csr_src,
                           int* __restrict__ cnt, int n) {
    int v = blockIdx.x * blockDim.x + threadIdx.x;
    if (v < n) {
        csr_src[row_ptr[v]] = v;   // self-loop at slot 0
        cnt[v] = 1;
    }
}

__global__ void k_scatter(const int* __restrict__ ei, const int* __restrict__ row_ptr,
                          int* __restrict__ cnt, int* __restrict__ csr_src, int E) {
    int e = blockIdx.x * blockDim.x + threadIdx.x;
    if (e < E) {
        int d = ei[E + e];
        int pos = row_ptr[d] + atomicAdd(&cnt[d], 1);
        csr_src[pos] = ei[e];
    }
}

// ---------------- input split: fp32 -> (bf16 hi, bf16 lo) ----------------

__global__ __launch_bounds__(256) void k_split(const float* __restrict__ X,
                                               unsigned short* __restrict__ Xh,
                                               unsigned short* __restrict__ Xl,
                                               int total4) {
    int i = blockIdx.x * blockDim.x + threadIdx.x;
    if (i >= total4) return;
    float4 f = ((const float4*)X)[i];
    ushort4 h, l;
    h.x = f2bf(f.x); l.x = f2bf(f.x - bf2f(h.x));
    h.y = f2bf(f.y); l.y = f2bf(f.y - bf2f(h.y));
    h.z = f2bf(f.z); l.z = f2bf(f.z - bf2f(h.z));
    h.w = f2bf(f.w); l.w = f2bf(f.w - bf2f(h.w));
    ((ushort4*)Xh)[i] = h;
    ((ushort4*)Xl)[i] = l;
}

// ------ weight transpose + split: W[K=256][N] fp32 -> WhT,WlT[N][256] bf16 ------

__global__ __launch_bounds__(256) void k_wsplit(const float* __restrict__ W,
                                                unsigned short* __restrict__ WhT,
                                                unsigned short* __restrict__ WlT,
                                                int N) {
    __shared__ float t[64][65];
    int kb = blockIdx.x * 64, nb = blockIdx.y * 64;
    int tid = threadIdx.x;
    int c = tid & 63, r4 = tid >> 6;
    #pragma unroll
    for (int it = 0; it < 16; ++it) {
        int r = it * 4 + r4;
        t[r][c] = W[(size_t)(kb + r) * N + nb + c];
    }
    __syncthreads();
    #pragma unroll
    for (int it = 0; it < 16; ++it) {
        int n = it * 4 + r4;
        int k = c;
        float f = t[k][n];
        unsigned short hi = f2bf(f);
        unsigned short lo = f2bf(f - bf2f(hi));
        WhT[(size_t)(nb + n) * NNODE_K + kb + k] = hi;
        WlT[(size_t)(nb + n) * NNODE_K + kb + k] = lo;
    }
}

// ---------------- split-bf16 MFMA GEMM: C = A[M,256] @ W[256,N] + bias ----------------
// 3 terms: Ah*Wh + Al*Wh + Ah*Wl. LDS tiles 128x64 bf16, XOR slot swizzle
// slot' = slot ^ (row&7) applied at stage time (global side) and read time.

#define GBM 128
#define GBN 128
#define GBK 64

__global__ __launch_bounds__(256) void gemm_mfma(
    const unsigned short* __restrict__ Ah, const unsigned short* __restrict__ Al,
    const unsigned short* __restrict__ WhT, const unsigned short* __restrict__ WlT,
    const float* __restrict__ bias, float* __restrict__ C, int M, int N) {
    __shared__ char smem[GBM * GBK * 2 * 2];   // 16 KB A + 16 KB B
    char* sA = smem;
    char* sB = smem + GBM * GBK * 2;
    int tid = threadIdx.x;
    int lane = tid & 63, wid = tid >> 6;
    int wr = wid >> 1, wc = wid & 1;           // wave -> 64x64 sub-tile
    int row0 = blockIdx.y * GBM, col0 = blockIdx.x * GBN;

    floatx4 acc[4][4];
    #pragma unroll
    for (int m = 0; m < 4; ++m)
        #pragma unroll
        for (int n = 0; n < 4; ++n)
            acc[m][n] = (floatx4){0.f, 0.f, 0.f, 0.f};

    const unsigned short* Asrc[3] = {Ah, Al, Ah};
    const unsigned short* Bsrc[3] = {WhT, WhT, WlT};

    for (int t = 0; t < 3; ++t) {
        const unsigned short* Ap = Asrc[t];
        const unsigned short* Bp = Bsrc[t];
        for (int k0 = 0; k0 < NNODE_K; k0 += GBK) {
            // stage A and B tiles: 1024 16B-chunks each, 4 per thread per tile.
            // chunk c: row = c>>3, slot = c&7; global slot = slot^(row&7) so the
            // LDS write stays linear and the read-side XOR sees the right data.
            #pragma unroll
            for (int it = 0; it < 4; ++it) {
                int c = it * 256 + tid;
                int row = c >> 3, slot = c & 7;
                int sl = slot ^ (row & 7);
                int gr = row0 + row; if (gr >= M) gr = M - 1;
                *(int4*)(sA + c * 16) =
                    *(const int4*)(Ap + (size_t)gr * NNODE_K + k0 + sl * 8);
                *(int4*)(sB + c * 16) =
                    *(const int4*)(Bp + (size_t)(col0 + row) * NNODE_K + k0 + sl * 8);
            }
            __syncthreads();
            #pragma unroll
            for (int kk = 0; kk < 2; ++kk) {
                short8v a[4], b[4];
                #pragma unroll
                for (int m = 0; m < 4; ++m) {
                    int ra = wr * 64 + m * 16 + (lane & 15);
                    int st = (kk * 4 + (lane >> 4)) ^ (ra & 7);
                    a[m] = *(const short8v*)(sA + ra * 128 + st * 16);
                }
                #pragma unroll
                for (int n = 0; n < 4; ++n) {
                    int rb = wc * 64 + n * 16 + (lane & 15);
                    int st = (kk * 4 + (lane >> 4)) ^ (rb & 7);
                    b[n] = *(const short8v*)(sB + rb * 128 + st * 16);
                }
                #pragma unroll
                for (int m = 0; m < 4; ++m)
                    #pragma unroll
                    for (int n = 0; n < 4; ++n)
                        acc[m][n] = __builtin_amdgcn_mfma_f32_16x16x32_bf16(
                            a[m], b[n], acc[m][n], 0, 0, 0);
            }
            __syncthreads();
        }
    }

    // epilogue: C/D frag mapping col=lane&15, row=(lane>>4)*4+reg (m89-verified)
    #pragma unroll
    for (int n = 0; n < 4; ++n) {
        int col = col0 + wc * 64 + n * 16 + (lane & 15);
        float bv = bias[col];
        #pragma unroll
        for (int m = 0; m < 4; ++m) {
            int rbase = row0 + wr * 64 + m * 16 + (lane >> 4) * 4;
            #pragma unroll
            for (int r = 0; r < 4; ++r) {
                int row = rbase + r;
                if (row < M) C[(size_t)row * N + col] = acc[m][n][r] + bv;
            }
        }
    }
}

// ---------------- aggregates, float4-per-lane, batched-edge gathers ----------------
// HD=256 (layers 0/1): lane owns cols 4l..4l+3, head = l>>3 (8-lane e-groups).
// 8 edge rows in flight per iteration. MODE 0: store splits of elu(agg+bias).
// MODE 1: store splits of elu(agg+bias) + resid, resid reconstructed from the
// input splits Sh/Sl (read before overwrite; same-thread elements only).

template<int MODE>
__global__ __launch_bounds__(256) void gat_agg_mid(
    const float* __restrict__ xl, const float* __restrict__ xr,
    const float* __restrict__ att, const int* __restrict__ row_ptr,
    const int* __restrict__ csr_src, const float* __restrict__ bias,
    unsigned short* __restrict__ Sh, unsigned short* __restrict__ Sl, int n) {
    int wid = threadIdx.x >> 6, lane = threadIdx.x & 63;
    int v = blockIdx.x * 4 + wid;
    if (v >= n) return;
    int idx = 4 * lane;
    float4 xrv  = *(const float4*)(xr + (size_t)v * 256 + idx);
    float4 attv = *(const float4*)(att + idx);
    float4 acc = make_float4(0.f, 0.f, 0.f, 0.f);
    float lsum = 0.f, mval = -INFINITY;

    int e0 = row_ptr[v], e1 = row_ptr[v + 1];
    for (int base = e0; base < e1; base += 8) {
        int cnt = e1 - base; if (cnt > 8) cnt = 8;
        int s[8];
        float4 xv[8];
        #pragma unroll
        for (int j = 0; j < 8; ++j) {
            int ee = base + j;
            s[j] = csr_src[ee < e1 ? ee : base];
        }
        #pragma unroll
        for (int j = 0; j < 8; ++j)
            xv[j] = *(const float4*)(xl + (size_t)s[j] * 256 + idx);
        #pragma unroll
        for (int j = 0; j < 8; ++j) {
            if (j >= cnt) break;   // wave-uniform
            float p = lrelu(xv[j].x + xrv.x) * attv.x + lrelu(xv[j].y + xrv.y) * attv.y +
                      lrelu(xv[j].z + xrv.z) * attv.z + lrelu(xv[j].w + xrv.w) * attv.w;
            p += __shfl_xor(p, 1); p += __shfl_xor(p, 2); p += __shfl_xor(p, 4);
            if (p > mval) {
                float sc = __expf(mval - p);
                acc.x *= sc; acc.y *= sc; acc.z *= sc; acc.w *= sc;
                lsum *= sc; mval = p;
            }
            float pe = __expf(p - mval);
            lsum += pe;
            acc.x += pe * xv[j].x; acc.y += pe * xv[j].y;
            acc.z += pe * xv[j].z; acc.w += pe * xv[j].w;
        }
    }

    float inv = 1.f / lsum;
    float4 bb = *(const float4*)(bias + idx);
    float o[4] = {acc.x * inv + bb.x, acc.y * inv + bb.y,
                  acc.z * inv + bb.z, acc.w * inv + bb.w};
    #pragma unroll
    for (int j = 0; j < 4; ++j) o[j] = o[j] > 0.f ? o[j] : (__expf(o[j]) - 1.f);
    if (MODE == 1) {
        ushort4 rh = *(const ushort4*)(Sh + (size_t)v * 256 + idx);
        ushort4 rl = *(const ushort4*)(Sl + (size_t)v * 256 + idx);
        o[0] += bf2f(rh.x) + bf2f(rl.x);
        o[1] += bf2f(rh.y) + bf2f(rl.y);
        o[2] += bf2f(rh.z) + bf2f(rl.z);
        o[3] += bf2f(rh.w) + bf2f(rl.w);
    }
    ushort4 hi, lo;
    hi.x = f2bf(o[0]); lo.x = f2bf(o[0] - bf2f(hi.x));
    hi.y = f2bf(o[1]); lo.y = f2bf(o[1] - bf2f(hi.y));
    hi.z = f2bf(o[2]); lo.z = f2bf(o[2] - bf2f(hi.z));
    hi.w = f2bf(o[3]); lo.w = f2bf(o[3] - bf2f(hi.w));
    *(ushort4*)(Sh + (size_t)v * 256 + idx) = hi;
    *(ushort4*)(Sl + (size_t)v * 256 + idx) = lo;
}

// HD=512 (layer 2), concat=False: lane owns cols {4l..4l+3} (head l>>4) and
// {256+4l..} (head 4+(l>>4)); 16-lane shuffle groups; 4 edge rows in flight;
// head-mean epilogue via cross-lane sum.

__global__ __launch_bounds__(256) void gat_agg_out(
    const float* __restrict__ xl, const float* __restrict__ xr,
    const float* __restrict__ att, const int* __restrict__ row_ptr,
    const int* __restrict__ csr_src, const float* __restrict__ bias,
    float* __restrict__ out, int n) {
    int wid = threadIdx.x >> 6, lane = threadIdx.x & 63;
    int v = blockIdx.x * 4 + wid;
    if (v >= n) return;
    int idx = 4 * lane;
    float4 xr0 = *(const float4*)(xr + (size_t)v * 512 + idx);
    float4 xr1 = *(const float4*)(xr + (size_t)v * 512 + 256 + idx);
    float4 at0 = *(const float4*)(att + idx);
    float4 at1 = *(const float4*)(att + 256 + idx);
    float4 a0 = make_float4(0.f, 0.f, 0.f, 0.f), a1 = a0;
    float ls0 = 0.f, ls1 = 0.f, m0 = -INFINITY, m1 = -INFINITY;

    int e0 = row_ptr[v], e1 = row_ptr[v + 1];
    for (int base = e0; base < e1; base += 4) {
        int cnt = e1 - base; if (cnt > 4) cnt = 4;
        int s[4];
        float4 x0[4], x1[4];
        #pragma unroll
        for (int j = 0; j < 4; ++j) {
            int ee = base + j;
            s[j] = csr_src[ee < e1 ? ee : base];
        }
        #pragma unroll
        for (int j = 0; j < 4; ++j) {
            x0[j] = *(const float4*)(xl + (size_t)s[j] * 512 + idx);
            x1[j] = *(const float4*)(xl + (size_t)s[j] * 512 + 256 + idx);
        }
        #pragma unroll
        for (int j = 0; j < 4; ++j) {
            if (j >= cnt) break;   // wave-uniform
            float p0 = lrelu(x0[j].x + xr0.x) * at0.x + lrelu(x0[j].y + xr0.y) * at0.y +
                       lrelu(x0[j].z + xr0.z) * at0.z + lrelu(x0[j].w + xr0.w) * at0.w;
            float p1 = lrelu(x1[j].x + xr1.x) * at1.x + lrelu(x1[j].y + xr1.y) * at1.y +
                       lrelu(x1[j].z + xr1.z) * at1.z + lrelu(x1[j].w + xr1.w) * at1.w;
            #pragma unroll
            for (int msk = 1; msk < 16; msk <<= 1) {
                p0 += __shfl_xor(p0, msk);
                p1 += __shfl_xor(p1, msk);
            }
            if (p0 > m0) {
                float sc = __expf(m0 - p0);
                a0.x *= sc; a0.y *= sc; a0.z *= sc; a0.w *= sc; ls0 *= sc; m0 = p0;
            }
            float pe0 = __expf(p0 - m0);
            ls0 += pe0;
            a0.x += pe0 * x0[j].x; a0.y += pe0 * x0[j].y;
            a0.z += pe0 * x0[j].z; a0.w += pe0 * x0[j].w;
            if (p1 > m1) {
                float sc = __expf(m1 - p1);
                a1.x *= sc; a1.y *= sc; a1.z *= sc; a1.w *= sc; ls1 *= sc; m1 = p1;
            }
            float pe1 = __expf(p1 - m1);
            ls1 += pe1;
            a1.x += pe1 * x1[j].x; a1.y += pe1 * x1[j].y;
            a1.z += pe1 * x1[j].z; a1.w += pe1 * x1[j].w;
        }
    }

    float i0 = 1.f / ls0, i1 = 1.f / ls1;
    float o[4] = {a0.x * i0 + a1.x * i1, a0.y * i0 + a1.y * i1,
                  a0.z * i0 + a1.z * i1, a0.w * i0 + a1.w * i1};
    #pragma unroll
    for (int j = 0; j < 4; ++j) {
        o[j] += __shfl_xor(o[j], 16);
        o[j] += __shfl_xor(o[j], 32);
    }
    if (lane < 16) {
        float4 bb = *(const float4*)(bias + idx);
        float4 res;
        res.x = o[0] * 0.125f + bb.x;
        res.y = o[1] * 0.125f + bb.y;
        res.z = o[2] * 0.125f + bb.z;
        res.w = o[3] * 0.125f + bb.w;
        *(float4*)(out + (size_t)v * 64 + idx) = res;
    }
}

// ---------------------------------------------------------------------------

extern "C" void kernel_launch(void* const* d_in, const int* in_sizes, int n_in,
                              void* d_out, int out_size, void* d_ws, size_t ws_size,
                              hipStream_t stream) {
    const float* x     = (const float*)d_in[0];
    const int*   ei    = (const int*)  d_in[1];
    const float* Wl0   = (const float*)d_in[2];
    const float* bl0   = (const float*)d_in[3];
    const float* Wr0   = (const float*)d_in[4];
    const float* br0   = (const float*)d_in[5];
    const float* att0  = (const float*)d_in[6];
    const float* bias0 = (const float*)d_in[7];
    const float* Wl1   = (const float*)d_in[8];
    const float* bl1   = (const float*)d_in[9];
    const float* Wr1   = (const float*)d_in[10];
    const float* br1   = (const float*)d_in[11];
    const float* att1  = (const float*)d_in[12];
    const float* bias1 = (const float*)d_in[13];
    const float* Wl2   = (const float*)d_in[14];
    const float* bl2   = (const float*)d_in[15];
    const float* Wr2   = (const float*)d_in[16];
    const float* br2   = (const float*)d_in[17];
    const float* att2  = (const float*)d_in[18];
    const float* bias2 = (const float*)d_in[19];

    const int N = in_sizes[0] / DIN;       // 20000
    const int E = in_sizes[1] / 2;         // 320000

    char* ws = (char*)d_ws;
    size_t off = 0;
    auto carve = [&](size_t bytes) {
        void* p = ws + off;
        off = (off + bytes + 15) & ~(size_t)15;
        return p;
    };
    int*            row_ptr = (int*)           carve((size_t)(N + 1) * 4);
    int*            cnt     = (int*)           carve((size_t)N * 4);
    int*            csr_src = (int*)           carve((size_t)(E + N) * 4);
    float*          xl      = (float*)         carve((size_t)N * 512 * 4);
    float*          xr      = (float*)         carve((size_t)N * 512 * 4);
    unsigned short* Ah      = (unsigned short*)carve((size_t)N * 256 * 2);
    unsigned short* Al      = (unsigned short*)carve((size_t)N * 256 * 2);
    unsigned short* WhT     = (unsigned short*)carve((size_t)512 * 256 * 2);
    unsigned short* WlT     = (unsigned short*)carve((size_t)512 * 256 * 2);

    float* outp = (float*)d_out;

    // ---- CSR build ----
    k_init_cnt<<<(N + 255) / 256, 256, 0, stream>>>(cnt, N);
    k_count   <<<(E + 255) / 256, 256, 0, stream>>>(ei, cnt, E);
    k_scan    <<<1, 256, 0, stream>>>(cnt, row_ptr, N);
    k_selfloop<<<(N + 255) / 256, 256, 0, stream>>>(row_ptr, csr_src, cnt, N);
    k_scatter <<<(E + 255) / 256, 256, 0, stream>>>(ei, row_ptr, cnt, csr_src, E);

    dim3 blk(256);
    const int aggGrid = (N + 3) / 4;
    dim3 gemmGrid256(2, (N + GBM - 1) / GBM);
    dim3 gemmGrid512(4, (N + GBM - 1) / GBM);
    dim3 wsGrid256(4, 4), wsGrid512(4, 8);

    // ---- input split ----
    k_split<<<(N * 256 / 4 + 255) / 256, blk, 0, stream>>>(x, Ah, Al, N * 256 / 4);

    // ---- layer 0 ----
    k_wsplit<<<wsGrid256, blk, 0, stream>>>(Wl0, WhT, WlT, 256);
    gemm_mfma<<<gemmGrid256, blk, 0, stream>>>(Ah, Al, WhT, WlT, bl0, xl, N, 256);
    k_wsplit<<<wsGrid256, blk, 0, stream>>>(Wr0, WhT, WlT, 256);
    gemm_mfma<<<gemmGrid256, blk, 0, stream>>>(Ah, Al, WhT, WlT, br0, xr, N, 256);
    gat_agg_mid<0><<<aggGrid, blk, 0, stream>>>(
        xl, xr, att0, row_ptr, csr_src, bias0, Ah, Al, N);

    // ---- layer 1 ----
    k_wsplit<<<wsGrid256, blk, 0, stream>>>(Wl1, WhT, WlT, 256);
    gemm_mfma<<<gemmGrid256, blk, 0, stream>>>(Ah, Al, WhT, WlT, bl1, xl, N, 256);
    k_wsplit<<<wsGrid256, blk, 0, stream>>>(Wr1, WhT, WlT, 256);
    gemm_mfma<<<gemmGrid256, blk, 0, stream>>>(Ah, Al, WhT, WlT, br1, xr, N, 256);
    gat_agg_mid<1><<<aggGrid, blk, 0, stream>>>(
        xl, xr, att1, row_ptr, csr_src, bias1, Ah, Al, N);

    // ---- layer 2 ----
    k_wsplit<<<wsGrid512, blk, 0, stream>>>(Wl2, WhT, WlT, 512);
    gemm_mfma<<<gemmGrid512, blk, 0, stream>>>(Ah, Al, WhT, WlT, bl2, xl, N, 512);
    k_wsplit<<<wsGrid512, blk, 0, stream>>>(Wr2, WhT, WlT, 512);
    gemm_mfma<<<gemmGrid512, blk, 0, stream>>>(Ah, Al, WhT, WlT, br2, xr, N, 512);
    gat_agg_out<<<aggGrid, blk, 0, stream>>>(
        xl, xr, att2, row_ptr, csr_src, bias2, outp, N);
}

// Round 9
// 565.645 us; speedup vs baseline: 1.6821x; 1.1614x over previous
//
#include <hip/hip_runtime.h>
#include <math.h>

// ---------------------------------------------------------------------------
// GATv2 backbone, round 9 (= round-8 design resubmitted through GPU timeout):
//   - GEMMs: 3-term split-bf16 MFMA, staged via global_load_lds width=16
//     (linear LDS dest + pre-swizzled per-lane global source), Wl/Wr merged
//     into one N-doubled GEMM per layer (3 dispatches).
//   - gat_agg_out: 8 edge-rows in flight.
//   - CSR scan: hierarchical 3-kernel scan.
// ---------------------------------------------------------------------------

#define DIN   256
#define NNODE_K 256   // K is 256 for every GEMM in this net

typedef __attribute__((ext_vector_type(8))) short short8v;
typedef __attribute__((ext_vector_type(4))) float floatx4;

typedef __attribute__((address_space(1))) void gas_t;
typedef __attribute__((address_space(3))) void las_t;
static __device__ __forceinline__ void gload_lds16(const void* g, void* l) {
    // direct global->LDS DMA, 16 B/lane; LDS dest = wave-uniform base + lane*16
    __builtin_amdgcn_global_load_lds((gas_t*)(uintptr_t)g, (las_t*)(uintptr_t)l,
                                     16, 0, 0);
}

static __device__ __forceinline__ unsigned short f2bf(float f) {
    unsigned int u = __float_as_uint(f);
    unsigned int r = (u + 0x7FFFu + ((u >> 16) & 1u)) >> 16;   // RNE
    return (unsigned short)r;
}
static __device__ __forceinline__ float bf2f(unsigned short h) {
    return __uint_as_float(((unsigned int)h) << 16);
}
static __device__ __forceinline__ float lrelu(float m) {
    return m > 0.f ? m : 0.2f * m;
}

// ---------------- CSR build ----------------

__global__ void k_init_cnt(int* cnt, int n) {
    int i = blockIdx.x * blockDim.x + threadIdx.x;
    if (i < n) cnt[i] = 1;   // self-loop pre-counted
}

__global__ void k_count(const int* __restrict__ ei, int* cnt, int E) {
    int e = blockIdx.x * blockDim.x + threadIdx.x;
    if (e < E) atomicAdd(&cnt[ei[E + e]], 1);   // dst row
}

// hierarchical scan: per-block inclusive scan + block sums
__global__ __launch_bounds__(256) void k_scan_blocks(
    const int* __restrict__ cnt, int* __restrict__ row_ptr,
    int* __restrict__ bsum, int n) {
    __shared__ int sm[256];
    int tid = threadIdx.x;
    int i = blockIdx.x * 256 + tid;
    int v = (i < n) ? cnt[i] : 0;
    sm[tid] = v;
    __syncthreads();
    for (int off = 1; off < 256; off <<= 1) {
        int t = (tid >= off) ? sm[tid - off] : 0;
        __syncthreads();
        sm[tid] += t;
        __syncthreads();
    }
    if (i < n) row_ptr[i + 1] = sm[tid];
    if (tid == 255) bsum[blockIdx.x] = sm[255];
}

// single block: exclusive scan of block sums (nb <= 256)
__global__ __launch_bounds__(256) void k_scan_tops(int* bsum, int nb) {
    __shared__ int sm[256];
    int tid = threadIdx.x;
    int v = (tid < nb) ? bsum[tid] : 0;
    sm[tid] = v;
    __syncthreads();
    for (int off = 1; off < 256; off <<= 1) {
        int t = (tid >= off) ? sm[tid - off] : 0;
        __syncthreads();
        sm[tid] += t;
        __syncthreads();
    }
    if (tid < nb) bsum[tid] = sm[tid] - v;   // exclusive
}

__global__ void k_scan_add(int* __restrict__ row_ptr,
                           const int* __restrict__ bsum, int n) {
    int i = blockIdx.x * 256 + threadIdx.x;
    if (i < n) row_ptr[i + 1] += bsum[blockIdx.x];
    if (i == 0) row_ptr[0] = 0;
}

__global__ void k_selfloop(const int* __restrict__ row_ptr, int* __restrict__ csr_src,
                           int* __restrict__ cnt, int n) {
    int v = blockIdx.x * blockDim.x + threadIdx.x;
    if (v < n) {
        csr_src[row_ptr[v]] = v;   // self-loop at slot 0
        cnt[v] = 1;
    }
}

__global__ void k_scatter(const int* __restrict__ ei, const int* __restrict__ row_ptr,
                          int* __restrict__ cnt, int* __restrict__ csr_src, int E) {
    int e = blockIdx.x * blockDim.x + threadIdx.x;
    if (e < E) {
        int d = ei[E + e];
        int pos = row_ptr[d] + atomicAdd(&cnt[d], 1);
        csr_src[pos] = ei[e];
    }
}

// ---------------- input split: fp32 -> (bf16 hi, bf16 lo) ----------------

__global__ __launch_bounds__(256) void k_split(const float* __restrict__ X,
                                               unsigned short* __restrict__ Xh,
                                               unsigned short* __restrict__ Xl,
                                               int total4) {
    int i = blockIdx.x * blockDim.x + threadIdx.x;
    if (i >= total4) return;
    float4 f = ((const float4*)X)[i];
    ushort4 h, l;
    h.x = f2bf(f.x); l.x = f2bf(f.x - bf2f(h.x));
    h.y = f2bf(f.y); l.y = f2bf(f.y - bf2f(h.y));
    h.z = f2bf(f.z); l.z = f2bf(f.z - bf2f(h.z));
    h.w = f2bf(f.w); l.w = f2bf(f.w - bf2f(h.w));
    ((ushort4*)Xh)[i] = h;
    ((ushort4*)Xl)[i] = l;
}

// ---- merged weight transpose+split: Wl,Wr[K=256][Nh] -> WT[2*Nh][256] bf16 ----

__global__ __launch_bounds__(256) void k_wsplit2(
    const float* __restrict__ Wl, const float* __restrict__ Wr,
    unsigned short* __restrict__ WhT, unsigned short* __restrict__ WlT, int Nh) {
    __shared__ float t[64][65];
    int kb = blockIdx.x * 64;
    int nbg = blockIdx.y * 64;                 // global output column block
    const float* W = (nbg < Nh) ? Wl : Wr;
    int nb = (nbg < Nh) ? nbg : nbg - Nh;      // column within source W
    int tid = threadIdx.x;
    int c = tid & 63, r4 = tid >> 6;
    #pragma unroll
    for (int it = 0; it < 16; ++it) {
        int r = it * 4 + r4;
        t[r][c] = W[(size_t)(kb + r) * Nh + nb + c];
    }
    __syncthreads();
    #pragma unroll
    for (int it = 0; it < 16; ++it) {
        int n = it * 4 + r4;
        int k = c;
        float f = t[k][n];
        unsigned short hi = f2bf(f);
        unsigned short lo = f2bf(f - bf2f(hi));
        WhT[(size_t)(nbg + n) * NNODE_K + kb + k] = hi;
        WlT[(size_t)(nbg + n) * NNODE_K + kb + k] = lo;
    }
}

// ---------------- split-bf16 MFMA GEMM: C = A[M,256] @ W[256,N] + bias ----------------
// 3 terms: Ah*Wh + Al*Wh + Ah*Wl. LDS tiles 128x64 bf16, XOR slot swizzle
// slot' = slot ^ (row&7): LDS stays linear, swizzle applied on the per-lane
// GLOBAL source address (global_load_lds-compatible) and on the read side.
// bias: col < HN -> bl[col], else br[col-HN] (merged Wl|Wr GEMM).

#define GBM 128
#define GBN 128
#define GBK 64

__global__ __launch_bounds__(256) void gemm_mfma(
    const unsigned short* __restrict__ Ah, const unsigned short* __restrict__ Al,
    const unsigned short* __restrict__ WhT, const unsigned short* __restrict__ WlT,
    const float* __restrict__ bl, const float* __restrict__ br, int HN,
    float* __restrict__ C, int M, int N) {
    __shared__ char smem[GBM * GBK * 2 * 2];   // 16 KB A + 16 KB B
    char* sA = smem;
    char* sB = smem + GBM * GBK * 2;
    int tid = threadIdx.x;
    int lane = tid & 63, wid = tid >> 6;
    int wr = wid >> 1, wc = wid & 1;           // wave -> 64x64 sub-tile
    int row0 = blockIdx.y * GBM, col0 = blockIdx.x * GBN;

    floatx4 acc[4][4];
    #pragma unroll
    for (int m = 0; m < 4; ++m)
        #pragma unroll
        for (int n = 0; n < 4; ++n)
            acc[m][n] = (floatx4){0.f, 0.f, 0.f, 0.f};

    const unsigned short* Asrc[3] = {Ah, Al, Ah};
    const unsigned short* Bsrc[3] = {WhT, WhT, WlT};

    for (int t = 0; t < 3; ++t) {
        const unsigned short* Ap = Asrc[t];
        const unsigned short* Bp = Bsrc[t];
        for (int k0 = 0; k0 < NNODE_K; k0 += GBK) {
            // stage A and B tiles via global_load_lds: chunk c = it*256+tid,
            // LDS dest linear at c*16 (wave-uniform base + lane*16), global
            // source pre-swizzled: slot read = (c&7) ^ (row&7).
            #pragma unroll
            for (int it = 0; it < 4; ++it) {
                int c = it * 256 + tid;
                int row = c >> 3, slot = c & 7;
                int sl = slot ^ (row & 7);
                int gr = row0 + row; if (gr >= M) gr = M - 1;
                char* dA = sA + (it * 256 + wid * 64) * 16;
                char* dB = sB + (it * 256 + wid * 64) * 16;
                gload_lds16(Ap + (size_t)gr * NNODE_K + k0 + sl * 8, dA);
                gload_lds16(Bp + (size_t)(col0 + row) * NNODE_K + k0 + sl * 8, dB);
            }
            __syncthreads();
            #pragma unroll
            for (int kk = 0; kk < 2; ++kk) {
                short8v a[4], b[4];
                #pragma unroll
                for (int m = 0; m < 4; ++m) {
                    int ra = wr * 64 + m * 16 + (lane & 15);
                    int st = (kk * 4 + (lane >> 4)) ^ (ra & 7);
                    a[m] = *(const short8v*)(sA + ra * 128 + st * 16);
                }
                #pragma unroll
                for (int n = 0; n < 4; ++n) {
                    int rb = wc * 64 + n * 16 + (lane & 15);
                    int st = (kk * 4 + (lane >> 4)) ^ (rb & 7);
                    b[n] = *(const short8v*)(sB + rb * 128 + st * 16);
                }
                #pragma unroll
                for (int m = 0; m < 4; ++m)
                    #pragma unroll
                    for (int n = 0; n < 4; ++n)
                        acc[m][n] = __builtin_amdgcn_mfma_f32_16x16x32_bf16(
                            a[m], b[n], acc[m][n], 0, 0, 0);
            }
            __syncthreads();
        }
    }

    // epilogue: C/D frag mapping col=lane&15, row=(lane>>4)*4+reg (m89-verified)
    #pragma unroll
    for (int n = 0; n < 4; ++n) {
        int col = col0 + wc * 64 + n * 16 + (lane & 15);
        float bv = (col < HN) ? bl[col] : br[col - HN];
        #pragma unroll
        for (int m = 0; m < 4; ++m) {
            int rbase = row0 + wr * 64 + m * 16 + (lane >> 4) * 4;
            #pragma unroll
            for (int r = 0; r < 4; ++r) {
                int row = rbase + r;
                if (row < M) C[(size_t)row * N + col] = acc[m][n][r] + bv;
            }
        }
    }
}

// ---------------- aggregates, float4-per-lane, batched-edge gathers ----------------
// xlr rows hold [xl | xr] (stride 512 for layers 0/1, 1024 for layer 2).
// HD=256 (layers 0/1): lane owns cols 4l..4l+3, head = l>>3 (8-lane e-groups).
// 8 edge rows in flight. MODE 0: store splits of elu(agg+bias).
// MODE 1: + residual reconstructed from input splits Sh/Sl (read before
// overwrite; same-thread elements only).

template<int MODE>
__global__ __launch_bounds__(256) void gat_agg_mid(
    const float* __restrict__ xlr, const float* __restrict__ att,
    const int* __restrict__ row_ptr, const int* __restrict__ csr_src,
    const float* __restrict__ bias,
    unsigned short* __restrict__ Sh, unsigned short* __restrict__ Sl, int n) {
    int wid = threadIdx.x >> 6, lane = threadIdx.x & 63;
    int v = blockIdx.x * 4 + wid;
    if (v >= n) return;
    int idx = 4 * lane;
    float4 xrv  = *(const float4*)(xlr + (size_t)v * 512 + 256 + idx);
    float4 attv = *(const float4*)(att + idx);
    float4 acc = make_float4(0.f, 0.f, 0.f, 0.f);
    float lsum = 0.f, mval = -INFINITY;

    int e0 = row_ptr[v], e1 = row_ptr[v + 1];
    for (int base = e0; base < e1; base += 8) {
        int cnt = e1 - base; if (cnt > 8) cnt = 8;
        int s[8];
        float4 xv[8];
        #pragma unroll
        for (int j = 0; j < 8; ++j) {
            int ee = base + j;
            s[j] = csr_src[ee < e1 ? ee : base];
        }
        #pragma unroll
        for (int j = 0; j < 8; ++j)
            xv[j] = *(const float4*)(xlr + (size_t)s[j] * 512 + idx);
        #pragma unroll
        for (int j = 0; j < 8; ++j) {
            if (j >= cnt) break;   // wave-uniform
            float p = lrelu(xv[j].x + xrv.x) * attv.x + lrelu(xv[j].y + xrv.y) * attv.y +
                      lrelu(xv[j].z + xrv.z) * attv.z + lrelu(xv[j].w + xrv.w) * attv.w;
            p += __shfl_xor(p, 1); p += __shfl_xor(p, 2); p += __shfl_xor(p, 4);
            if (p > mval) {
                float sc = __expf(mval - p);
                acc.x *= sc; acc.y *= sc; acc.z *= sc; acc.w *= sc;
                lsum *= sc; mval = p;
            }
            float pe = __expf(p - mval);
            lsum += pe;
            acc.x += pe * xv[j].x; acc.y += pe * xv[j].y;
            acc.z += pe * xv[j].z; acc.w += pe * xv[j].w;
        }
    }

    float inv = 1.f / lsum;
    float4 bb = *(const float4*)(bias + idx);
    float o[4] = {acc.x * inv + bb.x, acc.y * inv + bb.y,
                  acc.z * inv + bb.z, acc.w * inv + bb.w};
    #pragma unroll
    for (int j = 0; j < 4; ++j) o[j] = o[j] > 0.f ? o[j] : (__expf(o[j]) - 1.f);
    if (MODE == 1) {
        ushort4 rh = *(const ushort4*)(Sh + (size_t)v * 256 + idx);
        ushort4 rl = *(const ushort4*)(Sl + (size_t)v * 256 + idx);
        o[0] += bf2f(rh.x) + bf2f(rl.x);
        o[1] += bf2f(rh.y) + bf2f(rl.y);
        o[2] += bf2f(rh.z) + bf2f(rl.z);
        o[3] += bf2f(rh.w) + bf2f(rl.w);
    }
    ushort4 hi, lo;
    hi.x = f2bf(o[0]); lo.x = f2bf(o[0] - bf2f(hi.x));
    hi.y = f2bf(o[1]); lo.y = f2bf(o[1] - bf2f(hi.y));
    hi.z = f2bf(o[2]); lo.z = f2bf(o[2] - bf2f(hi.z));
    hi.w = f2bf(o[3]); lo.w = f2bf(o[3] - bf2f(hi.w));
    *(ushort4*)(Sh + (size_t)v * 256 + idx) = hi;
    *(ushort4*)(Sl + (size_t)v * 256 + idx) = lo;
}

// Layer 2 (HD=512 xl, concat=False): xlr stride 1024, xl = cols 0..511,
// xr = cols 512..1023. Lane owns {4l..4l+3} (head l>>4) and {256+4l..}
// (head 4+(l>>4)); 16-lane shuffle groups; 8 edge rows in flight;
// head-mean epilogue via cross-lane sum.

__global__ __launch_bounds__(256) void gat_agg_out(
    const float* __restrict__ xlr, const float* __restrict__ att,
    const int* __restrict__ row_ptr, const int* __restrict__ csr_src,
    const float* __restrict__ bias, float* __restrict__ out, int n) {
    int wid = threadIdx.x >> 6, lane = threadIdx.x & 63;
    int v = blockIdx.x * 4 + wid;
    if (v >= n) return;
    int idx = 4 * lane;
    float4 xr0 = *(const float4*)(xlr + (size_t)v * 1024 + 512 + idx);
    float4 xr1 = *(const float4*)(xlr + (size_t)v * 1024 + 768 + idx);
    float4 at0 = *(const float4*)(att + idx);
    float4 at1 = *(const float4*)(att + 256 + idx);
    float4 a0 = make_float4(0.f, 0.f, 0.f, 0.f), a1 = a0;
    float ls0 = 0.f, ls1 = 0.f, m0 = -INFINITY, m1 = -INFINITY;

    int e0 = row_ptr[v], e1 = row_ptr[v + 1];
    for (int base = e0; base < e1; base += 8) {
        int cnt = e1 - base; if (cnt > 8) cnt = 8;
        int s[8];
        float4 x0[8], x1[8];
        #pragma unroll
        for (int j = 0; j < 8; ++j) {
            int ee = base + j;
            s[j] = csr_src[ee < e1 ? ee : base];
        }
        #pragma unroll
        for (int j = 0; j < 8; ++j) {
            x0[j] = *(const float4*)(xlr + (size_t)s[j] * 1024 + idx);
            x1[j] = *(const float4*)(xlr + (size_t)s[j] * 1024 + 256 + idx);
        }
        #pragma unroll
        for (int j = 0; j < 8; ++j) {
            if (j >= cnt) break;   // wave-uniform
            float p0 = lrelu(x0[j].x + xr0.x) * at0.x + lrelu(x0[j].y + xr0.y) * at0.y +
                       lrelu(x0[j].z + xr0.z) * at0.z + lrelu(x0[j].w + xr0.w) * at0.w;
            float p1 = lrelu(x1[j].x + xr1.x) * at1.x + lrelu(x1[j].y + xr1.y) * at1.y +
                       lrelu(x1[j].z + xr1.z) * at1.z + lrelu(x1[j].w + xr1.w) * at1.w;
            #pragma unroll
            for (int msk = 1; msk < 16; msk <<= 1) {
                p0 += __shfl_xor(p0, msk);
                p1 += __shfl_xor(p1, msk);
            }
            if (p0 > m0) {
                float sc = __expf(m0 - p0);
                a0.x *= sc; a0.y *= sc; a0.z *= sc; a0.w *= sc; ls0 *= sc; m0 = p0;
            }
            float pe0 = __expf(p0 - m0);
            ls0 += pe0;
            a0.x += pe0 * x0[j].x; a0.y += pe0 * x0[j].y;
            a0.z += pe0 * x0[j].z; a0.w += pe0 * x0[j].w;
            if (p1 > m1) {
                float sc = __expf(m1 - p1);
                a1.x *= sc; a1.y *= sc; a1.z *= sc; a1.w *= sc; ls1 *= sc; m1 = p1;
            }
            float pe1 = __expf(p1 - m1);
            ls1 += pe1;
            a1.x += pe1 * x1[j].x; a1.y += pe1 * x1[j].y;
            a1.z += pe1 * x1[j].z; a1.w += pe1 * x1[j].w;
        }
    }

    float i0 = 1.f / ls0, i1 = 1.f / ls1;
    float o[4] = {a0.x * i0 + a1.x * i1, a0.y * i0 + a1.y * i1,
                  a0.z * i0 + a1.z * i1, a0.w * i0 + a1.w * i1};
    #pragma unroll
    for (int j = 0; j < 4; ++j) {
        o[j] += __shfl_xor(o[j], 16);
        o[j] += __shfl_xor(o[j], 32);
    }
    if (lane < 16) {
        float4 bb = *(const float4*)(bias + idx);
        float4 res;
        res.x = o[0] * 0.125f + bb.x;
        res.y = o[1] * 0.125f + bb.y;
        res.z = o[2] * 0.125f + bb.z;
        res.w = o[3] * 0.125f + bb.w;
        *(float4*)(out + (size_t)v * 64 + idx) = res;
    }
}

// ---------------------------------------------------------------------------

extern "C" void kernel_launch(void* const* d_in, const int* in_sizes, int n_in,
                              void* d_out, int out_size, void* d_ws, size_t ws_size,
                              hipStream_t stream) {
    const float* x     = (const float*)d_in[0];
    const int*   ei    = (const int*)  d_in[1];
    const float* Wl0   = (const float*)d_in[2];
    const float* bl0   = (const float*)d_in[3];
    const float* Wr0   = (const float*)d_in[4];
    const float* br0   = (const float*)d_in[5];
    const float* att0  = (const float*)d_in[6];
    const float* bias0 = (const float*)d_in[7];
    const float* Wl1   = (const float*)d_in[8];
    const float* bl1   = (const float*)d_in[9];
    const float* Wr1   = (const float*)d_in[10];
    const float* br1   = (const float*)d_in[11];
    const float* att1  = (const float*)d_in[12];
    const float* bias1 = (const float*)d_in[13];
    const float* Wl2   = (const float*)d_in[14];
    const float* bl2   = (const float*)d_in[15];
    const float* Wr2   = (const float*)d_in[16];
    const float* br2   = (const float*)d_in[17];
    const float* att2  = (const float*)d_in[18];
    const float* bias2 = (const float*)d_in[19];

    const int N = in_sizes[0] / DIN;       // 20000
    const int E = in_sizes[1] / 2;         // 320000
    const int NB = (N + 255) / 256;        // scan blocks (79)

    char* ws = (char*)d_ws;
    size_t off = 0;
    auto carve = [&](size_t bytes) {
        void* p = ws + off;
        off = (off + bytes + 15) & ~(size_t)15;
        return p;
    };
    int*            row_ptr = (int*)           carve((size_t)(N + 1) * 4);
    int*            cnt     = (int*)           carve((size_t)N * 4);
    int*            bsum    = (int*)           carve((size_t)256 * 4);
    int*            csr_src = (int*)           carve((size_t)(E + N) * 4);
    float*          xlr     = (float*)         carve((size_t)N * 1024 * 4);
    unsigned short* Ah      = (unsigned short*)carve((size_t)N * 256 * 2);
    unsigned short* Al      = (unsigned short*)carve((size_t)N * 256 * 2);
    unsigned short* WhT     = (unsigned short*)carve((size_t)1024 * 256 * 2);
    unsigned short* WlT     = (unsigned short*)carve((size_t)1024 * 256 * 2);

    float* outp = (float*)d_out;

    // ---- CSR build ----
    k_init_cnt   <<<NB, 256, 0, stream>>>(cnt, N);
    k_count      <<<(E + 255) / 256, 256, 0, stream>>>(ei, cnt, E);
    k_scan_blocks<<<NB, 256, 0, stream>>>(cnt, row_ptr, bsum, N);
    k_scan_tops  <<<1, 256, 0, stream>>>(bsum, NB);
    k_scan_add   <<<NB, 256, 0, stream>>>(row_ptr, bsum, N);
    k_selfloop   <<<NB, 256, 0, stream>>>(row_ptr, csr_src, cnt, N);
    k_scatter    <<<(E + 255) / 256, 256, 0, stream>>>(ei, row_ptr, cnt, csr_src, E);

    dim3 blk(256);
    const int aggGrid = (N + 3) / 4;
    dim3 gemmGrid512(4, (N + GBM - 1) / GBM);    // N=512 merged
    dim3 gemmGrid1024(8, (N + GBM - 1) / GBM);   // N=1024 merged
    dim3 wsGrid512(4, 8), wsGrid1024(4, 16);

    // ---- input split ----
    k_split<<<(N * 256 / 4 + 255) / 256, blk, 0, stream>>>(x, Ah, Al, N * 256 / 4);

    // ---- layer 0 ----
    k_wsplit2<<<wsGrid512, blk, 0, stream>>>(Wl0, Wr0, WhT, WlT, 256);
    gemm_mfma<<<gemmGrid512, blk, 0, stream>>>(Ah, Al, WhT, WlT, bl0, br0, 256,
                                               xlr, N, 512);
    gat_agg_mid<0><<<aggGrid, blk, 0, stream>>>(
        xlr, att0, row_ptr, csr_src, bias0, Ah, Al, N);

    // ---- layer 1 ----
    k_wsplit2<<<wsGrid512, blk, 0, stream>>>(Wl1, Wr1, WhT, WlT, 256);
    gemm_mfma<<<gemmGrid512, blk, 0, stream>>>(Ah, Al, WhT, WlT, bl1, br1, 256,
                                               xlr, N, 512);
    gat_agg_mid<1><<<aggGrid, blk, 0, stream>>>(
        xlr, att1, row_ptr, csr_src, bias1, Ah, Al, N);

    // ---- layer 2 ----
    k_wsplit2<<<wsGrid1024, blk, 0, stream>>>(Wl2, Wr2, WhT, WlT, 512);
    gemm_mfma<<<gemmGrid1024, blk, 0, stream>>>(Ah, Al, WhT, WlT, bl2, br2, 512,
                                                xlr, N, 1024);
    gat_agg_out<<<aggGrid, blk, 0, stream>>>(
        xlr, att2, row_ptr, csr_src, bias2, outp, N);
}